// Round 19
// baseline (144.383 us; speedup 1.0000x reference)
//
#include <hip/hip_runtime.h>
#include <hip/hip_bf16.h>

typedef __bf16 bf16;
typedef __attribute__((ext_vector_type(8))) __bf16 bf16x8;
typedef __attribute__((ext_vector_type(2))) __bf16 bf16x2;
typedef __attribute__((ext_vector_type(4))) float f32x4;
typedef __attribute__((ext_vector_type(4))) unsigned int uint4v;

#define C_NODES 63
#define F_DIM   250
#define NEG_SLOPE 0.2f
#define BS 16              // batches per persistent block; grid 256 = 1/CU

// LDS map (139776 B -> 1 block/CU; 160 KiB CU limit; 128KB+ precedent: m201):
//   [0, 65520)        SLAB0: X f32, 63 rows x 1040 B (DMA bytes [0,992),
//                     tail 248/249 at [992,1000), zeros [1000,1024))
//   [65536, 131056)   SLAB1: double buffer
//   [131072, 131328)  AS: a_s[64] f32
//   [131328, 131584)  AD: a_d[64] f32
//   [131584, 139776)  ALPHA: alpha[64][64] bf16 (swz, 128 B rows)
#define ROWB      1040
#define SLAB0     0
#define SLAB1     65536
#define OFF_AS    131072
#define OFF_AD    131328
#define ALPHA_B   131584
#define LDS_BYTES 139776

__device__ __forceinline__ int swz(int a) { return a ^ ((a >> 3) & 0x70); }

typedef const __attribute__((address_space(1))) void* gas_t;
typedef __attribute__((address_space(3))) void* las_t;
__device__ __forceinline__ void dma16(const void* g, void* l) {
    __builtin_amdgcn_global_load_lds((gas_t)g, (las_t)l, 16, 0, 0);
}

// lgkm-only barrier: DMA/stores (vmcnt) stay in flight across phases.
__device__ __forceinline__ void bar_lgkm() {
    asm volatile("s_waitcnt lgkmcnt(0)" ::: "memory");
    __builtin_amdgcn_s_barrier();
    __builtin_amdgcn_sched_barrier(0);
}

// Pack W (250x250 f32) into bf16 MFMA-B fragment order, padded to 256x256.
// Columns 250/251 hold ws = W@att_src and wd = W@att_dst, so GEMM1 emits the
// per-node scores a_s, a_d directly. Rows k>=250 are zero (kills A-garbage).
extern "C" __global__ __launch_bounds__(256)
void gat_prep(const float* __restrict__ W, const float* __restrict__ att_src,
              const float* __restrict__ att_dst, bf16* __restrict__ Wp) {
    int i = blockIdx.x * 256 + threadIdx.x;   // 0..65535
    int tile = i >> 9;
    int ln   = (i >> 3) & 63;
    int j    = i & 7;
    int kt = tile >> 4, nt = tile & 15;
    int k = kt * 32 + (ln >> 4) * 8 + j;
    int n = nt * 16 + (ln & 15);
    float v = 0.f;
    if (k < F_DIM) {
        if (n < F_DIM) {
            v = W[k * F_DIM + n];
        } else if (n == F_DIM || n == F_DIM + 1) {
            const float* att = (n == F_DIM) ? att_src : att_dst;
            float s = 0.f;
            for (int o = 0; o < F_DIM; ++o) s = fmaf(W[k * F_DIM + o], att[o], s);
            v = s;
        }
    }
    Wp[i] = (bf16)v;
}

extern "C" __global__ __launch_bounds__(512, 2)
void gat_main(const float* __restrict__ x, const bf16* __restrict__ Wp,
              const float* __restrict__ bias, float* __restrict__ out)
{
    __shared__ __align__(16) unsigned char smem[LDS_BYTES];
    const int tid  = threadIdx.x;
    const int lane = tid & 63;
    const int w    = tid >> 6;        // wave id 0..7
    const int fl   = lane & 15;
    const int fh   = lane >> 4;
    const int b0   = blockIdx.x * BS;

    const bf16x8* wpv = (const bf16x8*)Wp;

    float bv0, bv1;
    { int f = w * 32 + fl;      bv0 = (f < F_DIM) ? bias[f] : 0.f;
      f += 16;                  bv1 = (f < F_DIM) ? bias[f] : 0.f; }

    // zero cols 250-255 of every row, both slabs (once)
    if (tid < 63) {
        *(unsigned long long*)(smem + SLAB0 + tid * ROWB + 1000) = 0ull;
        *(f32x4*)(smem + SLAB0 + tid * ROWB + 1008) = (f32x4){0.f, 0.f, 0.f, 0.f};
        *(unsigned long long*)(smem + SLAB1 + tid * ROWB + 1000) = 0ull;
        *(f32x4*)(smem + SLAB1 + tid * ROWB + 1008) = (f32x4){0.f, 0.f, 0.f, 0.f};
    }

    // prologue: stage slab0 (b0) then slab1 (b0+1); tail loads precede DMAs
    // so each tail ds_write's implicit wait is vmcnt(8), never 0.
    {
        const float* xb = x + (size_t)b0 * (C_NODES * F_DIM);
        float2 tl0 = {0.f, 0.f};
        if (tid < 63) tl0 = *(const float2*)(xb + tid * F_DIM + 248);
#pragma unroll
        for (int rr = 0; rr < 8; ++rr) {
            int r = w * 8 + rr;
            if (r < 63 && lane < 62)
                dma16(xb + r * F_DIM + lane * 4, smem + SLAB0 + r * ROWB);
        }
        if (tid < 63) *(float2*)(smem + SLAB0 + tid * ROWB + 992) = tl0;
    }
    {
        const float* xb = x + (size_t)(b0 + 1) * (C_NODES * F_DIM);
        float2 tl1 = {0.f, 0.f};
        if (tid < 63) tl1 = *(const float2*)(xb + tid * F_DIM + 248);
#pragma unroll
        for (int rr = 0; rr < 8; ++rr) {
            int r = w * 8 + rr;
            if (r < 63 && lane < 62)
                dma16(xb + r * F_DIM + lane * 4, smem + SLAB1 + r * ROWB);
        }
        if (tid < 63) *(float2*)(smem + SLAB1 + tid * ROWB + 992) = tl1;
    }
    bar_lgkm();   // slab0 complete (tl1's vmcnt(8) drained DMA0) + visible

    // prologue CA: GEMM1(b0) -> gacc; ASAD(b0)
    f32x4 gacc[4][2];
#pragma unroll
    for (int mt = 0; mt < 4; ++mt) {
        gacc[mt][0] = (f32x4){0.f, 0.f, 0.f, 0.f};
        gacc[mt][1] = (f32x4){0.f, 0.f, 0.f, 0.f};
    }
#pragma unroll 2
    for (int kt = 0; kt < 8; ++kt) {
        bf16x8 bw0 = wpv[(kt * 16 + w * 2)     * 64 + lane];
        bf16x8 bw1 = wpv[(kt * 16 + w * 2 + 1) * 64 + lane];
#pragma unroll
        for (int mt = 0; mt < 4; ++mt) {
            int row = mt * 16 + fl;
            bf16x8 af;
            if (row < C_NODES) {
                const f32x4* p = (const f32x4*)(smem + SLAB0 + row * ROWB + kt * 128 + fh * 32);
                f32x4 lo = p[0], hi = p[1];
                af = (bf16x8){ (bf16)lo.x, (bf16)lo.y, (bf16)lo.z, (bf16)lo.w,
                               (bf16)hi.x, (bf16)hi.y, (bf16)hi.z, (bf16)hi.w };
            } else {
                af = (bf16x8){(bf16)0.f,(bf16)0.f,(bf16)0.f,(bf16)0.f,
                              (bf16)0.f,(bf16)0.f,(bf16)0.f,(bf16)0.f};
            }
            gacc[mt][0] = __builtin_amdgcn_mfma_f32_16x16x32_bf16(af, bw0, gacc[mt][0], 0, 0, 0);
            gacc[mt][1] = __builtin_amdgcn_mfma_f32_16x16x32_bf16(af, bw1, gacc[mt][1], 0, 0, 0);
        }
    }
    if (w == 7 && (fl == 10 || fl == 11)) {
        float* dst = (float*)(smem + (fl == 10 ? OFF_AS : OFF_AD));
#pragma unroll
        for (int mt = 0; mt < 4; ++mt) {
            f32x4 v = gacc[mt][1];
#pragma unroll
            for (int q = 0; q < 4; ++q) dst[mt * 16 + fh * 4 + q] = v[q];
        }
    }
    bar_lgkm();   // AS/AD(b0) visible

#pragma unroll 1
    for (int i = 0; i < BS; ++i) {
        const int b = b0 + i;
        const int slabNext = ((i + 1) & 1) ? SLAB1 : SLAB0;
        const int slabDma  = (i & 1) ? SLAB1 : SLAB0;

        // ---- B(i): DMA(i+2)->slab[i&1]; transpose(i); softmax(i); bar ----
        float2 tl = {0.f, 0.f};
        const bool dmaEn = (i + 2 < BS);
        if (dmaEn) {
            const float* xn = x + (size_t)(b + 2) * (C_NODES * F_DIM);
            if (tid < 63) tl = *(const float2*)(xn + tid * F_DIM + 248);
#pragma unroll
            for (int rr = 0; rr < 8; ++rr) {
                int r = w * 8 + rr;
                if (r < 63 && lane < 62)
                    dma16(xn + r * F_DIM + lane * 4, smem + slabDma + r * ROWB);
            }
        }
        unsigned int pk[4][2][2];
#pragma unroll
        for (int mt = 0; mt < 4; ++mt)
#pragma unroll
            for (int nti = 0; nti < 2; ++nti) {
                f32x4 v = gacc[mt][nti];
                bf16x2 p0 = { (bf16)v.x, (bf16)v.y };
                bf16x2 p1 = { (bf16)v.z, (bf16)v.w };
                pk[mt][nti][0] = __builtin_bit_cast(unsigned int, p0);
                pk[mt][nti][1] = __builtin_bit_cast(unsigned int, p1);
            }
        const int LA = ((fh & 1) << 5) + fl;
        const int LB = LA + 16;
        const bool fhHi = (fh & 2) != 0;
        uint4v hb[2][2];
#pragma unroll
        for (int nti = 0; nti < 2; ++nti)
#pragma unroll
            for (int kt2 = 0; kt2 < 2; ++kt2) {
                unsigned int u[4];
#pragma unroll
                for (int h = 0; h < 2; ++h) {
                    unsigned int a0 = __shfl(pk[kt2 * 2][nti][h],     LA);
                    unsigned int a1 = __shfl(pk[kt2 * 2 + 1][nti][h], LA);
                    u[h] = fhHi ? a1 : a0;
                    unsigned int c0 = __shfl(pk[kt2 * 2][nti][h],     LB);
                    unsigned int c1 = __shfl(pk[kt2 * 2 + 1][nti][h], LB);
                    u[2 + h] = fhHi ? c1 : c0;
                }
                hb[nti][kt2] = (uint4v){u[0], u[1], u[2], u[3]};
            }
        {
            const float* AS  = (const float*)(smem + OFF_AS);
            const float* ADp = (const float*)(smem + OFF_AD);
            int d = tid >> 3;
            int c = tid & 7;
            float ad_v = ADp[d];
            f32x4 a0 = *(const f32x4*)(AS + c * 8);
            f32x4 a1 = *(const f32x4*)(AS + c * 8 + 4);
            float p[8];
#pragma unroll
            for (int k = 0; k < 4; ++k) {
                float e;
                e = a0[k] + ad_v; p[k]     = (e > 0.f) ? e : NEG_SLOPE * e;
                e = a1[k] + ad_v; p[4 + k] = (e > 0.f) ? e : NEG_SLOPE * e;
            }
            if (c == 7) p[7] = -3.0e38f;   // s=63 excluded (63 sources)
            float md = p[0];
#pragma unroll
            for (int k = 1; k < 8; ++k) md = fmaxf(md, p[k]);
            md = fmaxf(md, __shfl_xor(md, 1));
            md = fmaxf(md, __shfl_xor(md, 2));
            md = fmaxf(md, __shfl_xor(md, 4));
            float sum = 0.f;
#pragma unroll
            for (int k = 0; k < 8; ++k) { p[k] = __expf(p[k] - md); sum += p[k]; }
            sum += __shfl_xor(sum, 1);
            sum += __shfl_xor(sum, 2);
            sum += __shfl_xor(sum, 4);
            float rz = 1.f / sum;
            bf16x8 pkv;
#pragma unroll
            for (int k = 0; k < 8; ++k) pkv[k] = (bf16)(p[k] * rz);
            *(bf16x8*)(smem + swz(ALPHA_B + d * 128 + c * 16)) = pkv;
        }
        if (dmaEn) {
            // implicit vmcnt(8) here drains DMA(i+1); DMA(i+2) keeps flying
            if (tid < 63) *(float2*)(smem + slabDma + tid * ROWB + 992) = tl;
        } else if (i + 1 < BS) {
            asm volatile("s_waitcnt vmcnt(0)" ::: "memory");  // drain DMA(i+1)
        }
        bar_lgkm();   // alpha(i) + slab[(i+1)&1] visible

        // ---- CA(i): GEMM2(i); stores(i); GEMM1(i+1); ASAD(i+1); bar ----
#pragma unroll
        for (int mt = 0; mt < 4; ++mt) {
            gacc[mt][0] = (f32x4){0.f, 0.f, 0.f, 0.f};
            gacc[mt][1] = (f32x4){0.f, 0.f, 0.f, 0.f};
        }
#pragma unroll
        for (int ks = 0; ks < 2; ++ks) {
            int kk = ks * 32 + fh * 8;
            bf16x8 h0 = __builtin_bit_cast(bf16x8, hb[0][ks]);
            bf16x8 h1 = __builtin_bit_cast(bf16x8, hb[1][ks]);
#pragma unroll
            for (int mt = 0; mt < 4; ++mt) {
                bf16x8 aal = *(const bf16x8*)(smem + swz(ALPHA_B + (mt * 16 + fl) * 128 + kk * 2));
                gacc[mt][0] = __builtin_amdgcn_mfma_f32_16x16x32_bf16(aal, h0, gacc[mt][0], 0, 0, 0);
                gacc[mt][1] = __builtin_amdgcn_mfma_f32_16x16x32_bf16(aal, h1, gacc[mt][1], 0, 0, 0);
            }
        }
        float* ob = out + (size_t)b * (C_NODES * F_DIM);
#pragma unroll
        for (int mt = 0; mt < 4; ++mt) {
#pragma unroll
            for (int q = 0; q < 4; ++q) {
                int r = mt * 16 + fh * 4 + q;
                if (r < C_NODES) {
                    int f = w * 32 + fl;
                    ob[r * F_DIM + f] = gacc[mt][0][q] + bv0;
                    f += 16;
                    if (f < F_DIM) ob[r * F_DIM + f] = gacc[mt][1][q] + bv1;
                }
            }
        }
        if (i + 1 < BS) {
#pragma unroll
            for (int mt = 0; mt < 4; ++mt) {
                gacc[mt][0] = (f32x4){0.f, 0.f, 0.f, 0.f};
                gacc[mt][1] = (f32x4){0.f, 0.f, 0.f, 0.f};
            }
#pragma unroll 2
            for (int kt = 0; kt < 8; ++kt) {
                bf16x8 bw0 = wpv[(kt * 16 + w * 2)     * 64 + lane];
                bf16x8 bw1 = wpv[(kt * 16 + w * 2 + 1) * 64 + lane];
#pragma unroll
                for (int mt = 0; mt < 4; ++mt) {
                    int row = mt * 16 + fl;
                    bf16x8 af;
                    if (row < C_NODES) {
                        const f32x4* p = (const f32x4*)(smem + slabNext + row * ROWB + kt * 128 + fh * 32);
                        f32x4 lo = p[0], hi = p[1];
                        af = (bf16x8){ (bf16)lo.x, (bf16)lo.y, (bf16)lo.z, (bf16)lo.w,
                                       (bf16)hi.x, (bf16)hi.y, (bf16)hi.z, (bf16)hi.w };
                    } else {
                        af = (bf16x8){(bf16)0.f,(bf16)0.f,(bf16)0.f,(bf16)0.f,
                                      (bf16)0.f,(bf16)0.f,(bf16)0.f,(bf16)0.f};
                    }
                    gacc[mt][0] = __builtin_amdgcn_mfma_f32_16x16x32_bf16(af, bw0, gacc[mt][0], 0, 0, 0);
                    gacc[mt][1] = __builtin_amdgcn_mfma_f32_16x16x32_bf16(af, bw1, gacc[mt][1], 0, 0, 0);
                }
            }
            if (w == 7 && (fl == 10 || fl == 11)) {
                float* dst = (float*)(smem + (fl == 10 ? OFF_AS : OFF_AD));
#pragma unroll
                for (int mt = 0; mt < 4; ++mt) {
                    f32x4 v = gacc[mt][1];
#pragma unroll
                    for (int q = 0; q < 4; ++q) dst[mt * 16 + fh * 4 + q] = v[q];
                }
            }
        }
        bar_lgkm();
    }
}

extern "C" void kernel_launch(void* const* d_in, const int* in_sizes, int n_in,
                              void* d_out, int out_size, void* d_ws, size_t ws_size,
                              hipStream_t stream) {
    const float* x       = (const float*)d_in[0];
    const float* W       = (const float*)d_in[1];
    const float* att_src = (const float*)d_in[2];
    const float* att_dst = (const float*)d_in[3];
    const float* bias    = (const float*)d_in[4];
    float* out = (float*)d_out;
    bf16* Wp = (bf16*)d_ws;   // 65536 bf16 = 128 KB packed W (+score cols)

    gat_prep<<<256, 256, 0, stream>>>(W, att_src, att_dst, Wp);
    gat_main<<<256, 512, 0, stream>>>(x, Wp, bias, out);
}

// Round 20
// 133.877 us; speedup vs baseline: 1.0785x; 1.0785x over previous
//
#include <hip/hip_runtime.h>
#include <hip/hip_bf16.h>

typedef __bf16 bf16;
typedef __attribute__((ext_vector_type(8))) __bf16 bf16x8;
typedef __attribute__((ext_vector_type(4))) __bf16 bf16x4;
typedef __attribute__((ext_vector_type(2))) __bf16 bf16x2;
typedef __attribute__((ext_vector_type(4))) float f32x4;

#define C_NODES 63
#define F_DIM   250
#define NEG_SLOPE 0.2f
#define BS 16              // batches per persistent block; grid 256 = 1/CU

// LDS map (139264 B -> 1 block/CU):
//   [0, 65520)        SLAB: X f32, 63 rows x 1040 B. DMA fills [0,992) per
//                     row; tail 248/249 reg-staged at [992,1000);
//                     zeros [1000,1024) (cols 250-255, set once).
//   [65536, 98304)    AFR: bf16 MFMA A-frags (swzA). Fully rewritten by the
//                     conversion pass each batch except row 63 (guarded once).
//   [98304, 130304)   HSB: Hs[f][s] bf16, f<250 (swz row-local)
//   [130304, 130560)  AS: a_s[64] f32
//   [130560, 130816)  AD: a_d[64] f32
//   [131072, 139264)  ALPHA: alpha[64][64] bf16 (swz, 128 B rows)
#define ROWB      1040
#define SLAB      0
#define AFR_B     65536
#define HSB       98304
#define OFF_AS    130304
#define OFF_AD    130560
#define ALPHA_B   131072
#define LDS_BYTES 139264

__device__ __forceinline__ int swz(int a) { return a ^ ((a >> 3) & 0x70); }
// A-frag swizzle (local offset within AFR): bank-spread writes/reads.
__device__ __forceinline__ int swzA(int a) {
    return a ^ ((((a >> 8) & 3) ^ ((a >> 10) & 3)) << 4) ^ (((a >> 12) & 1) << 6);
}

typedef const __attribute__((address_space(1))) void* gas_t;
typedef __attribute__((address_space(3))) void* las_t;
__device__ __forceinline__ void dma16(const void* g, void* l) {
    __builtin_amdgcn_global_load_lds((gas_t)g, (las_t)l, 16, 0, 0);
}

// lgkm-only barrier: DMA/stores (vmcnt) stay in flight across phases.
__device__ __forceinline__ void bar_lgkm() {
    asm volatile("s_waitcnt lgkmcnt(0)" ::: "memory");
    __builtin_amdgcn_s_barrier();
    __builtin_amdgcn_sched_barrier(0);
}

// Wave-local conversion: wave w converts its own DMA'd rows w*8..w*8+7 from
// f32 slab to bf16 A-fragments. Lane covers cols lane*4..lane*4+3 (lane 62
// picks up tail 248/249 + zeros 250/251, lane 63 the zero cols 252-255).
__device__ __forceinline__ void conv_rows(unsigned char* smem, int w, int lane) {
#pragma unroll
    for (int rr = 0; rr < 8; ++rr) {
        int r = w * 8 + rr;
        if (r < C_NODES) {     // uniform per wave: wave 7 skips rr=7
            f32x4 v = *(const f32x4*)(smem + SLAB + r * ROWB + lane * 16);
            int c = lane * 4;
            int dl = (r & 15) | (((c >> 3) & 3) << 4);
            int base = AFR_B + swzA((((r >> 4) * 8 + (c >> 5)) << 10)
                                    + dl * 16 + (c & 4) * 2);
            bf16x4 o = { (bf16)v.x, (bf16)v.y, (bf16)v.z, (bf16)v.w };
            *(bf16x4*)(smem + base) = o;
        }
    }
}

// Pack W (250x250 f32) into bf16 MFMA-B fragment order, padded to 256x256.
// Columns 250/251 hold ws = W@att_src and wd = W@att_dst, so GEMM1 emits the
// per-node scores a_s, a_d directly. Rows k>=250 are zero (kills A-garbage).
extern "C" __global__ __launch_bounds__(256)
void gat_prep(const float* __restrict__ W, const float* __restrict__ att_src,
              const float* __restrict__ att_dst, bf16* __restrict__ Wp) {
    int i = blockIdx.x * 256 + threadIdx.x;   // 0..65535
    int tile = i >> 9;
    int ln   = (i >> 3) & 63;
    int j    = i & 7;
    int kt = tile >> 4, nt = tile & 15;
    int k = kt * 32 + (ln >> 4) * 8 + j;
    int n = nt * 16 + (ln & 15);
    float v = 0.f;
    if (k < F_DIM) {
        if (n < F_DIM) {
            v = W[k * F_DIM + n];
        } else if (n == F_DIM || n == F_DIM + 1) {
            const float* att = (n == F_DIM) ? att_src : att_dst;
            float s = 0.f;
            for (int o = 0; o < F_DIM; ++o) s = fmaf(W[k * F_DIM + o], att[o], s);
            v = s;
        }
    }
    Wp[i] = (bf16)v;
}

// 512 threads = 8 waves; wave w owns output cols [w*32, w*32+32).
// Persistent BS=16; phases A|B|D, 3 lgkm-only barriers; DMA f32 slab ->
// wave-local bf16 conversion -> half the GEMM1 LDS reads; Hs via LDS
// (cheaper on the DS pipe than the shuffle transpose).
extern "C" __global__ __launch_bounds__(512, 2)
void gat_main(const float* __restrict__ x, const bf16* __restrict__ Wp,
              const float* __restrict__ bias, float* __restrict__ out)
{
    __shared__ __align__(16) unsigned char smem[LDS_BYTES];
    const int tid  = threadIdx.x;
    const int lane = tid & 63;
    const int w    = tid >> 6;        // wave id 0..7
    const int fl   = lane & 15;
    const int fh   = lane >> 4;
    const int b0   = blockIdx.x * BS;

    const bf16x8* wpv = (const bf16x8*)Wp;

    float bv0, bv1;
    { int f = w * 32 + fl;      bv0 = (f < F_DIM) ? bias[f] : 0.f;
      f += 16;                  bv1 = (f < F_DIM) ? bias[f] : 0.f; }

    // one-time guards: slab zero cols 250-255; AFR row-63 slots (conv never
    // writes row 63; everything else is rewritten every batch).
    if (tid < 63) {
        *(unsigned long long*)(smem + SLAB + tid * ROWB + 1000) = 0ull;
        *(f32x4*)(smem + SLAB + tid * ROWB + 1008) = (f32x4){0.f, 0.f, 0.f, 0.f};
    } else if (tid < 96) {
        int idx = tid - 64;
        int base = AFR_B + swzA(((24 + (idx >> 2)) << 10) + ((((idx & 3) << 4) | 15) * 16));
        *(f32x4*)(smem + base) = (f32x4){0.f, 0.f, 0.f, 0.f};
    }

    // prime: stage slab(b0) via DMA + reg tail, then convert to AFR
    {
        const float* xb = x + (size_t)b0 * (C_NODES * F_DIM);
        float2 tl0 = {0.f, 0.f};
        if (tid < 63) tl0 = *(const float2*)(xb + tid * F_DIM + 248);
#pragma unroll
        for (int rr = 0; rr < 8; ++rr) {
            int r = w * 8 + rr;
            if (r < 63 && lane < 62)
                dma16(xb + r * F_DIM + lane * 4, smem + SLAB + r * ROWB);
        }
        if (tid < 63) *(float2*)(smem + SLAB + tid * ROWB + 992) = tl0;
    }
    asm volatile("s_waitcnt vmcnt(0)" ::: "memory");
    __syncthreads();           // slab(b0) fully visible (incl. tail by wave 0)
    conv_rows(smem, w, lane);
    bar_lgkm();                // AFR(b0) visible

#pragma unroll 1
    for (int i = 0; i < BS; ++i) {
        const int b = b0 + i;
        const bool pfen = (i + 1 < BS);
        const float* xnext = x + (size_t)(b + 1) * (C_NODES * F_DIM);

        // ---- A: GEMM1 from AFR (bf16); AS/AD extract (w7); bar1 ----
        f32x4 gacc[4][2];
#pragma unroll
        for (int mt = 0; mt < 4; ++mt) {
            gacc[mt][0] = (f32x4){0.f, 0.f, 0.f, 0.f};
            gacc[mt][1] = (f32x4){0.f, 0.f, 0.f, 0.f};
        }
#pragma unroll 2
        for (int kt = 0; kt < 8; ++kt) {
            bf16x8 bw0 = wpv[(kt * 16 + w * 2)     * 64 + lane];
            bf16x8 bw1 = wpv[(kt * 16 + w * 2 + 1) * 64 + lane];
#pragma unroll
            for (int mt = 0; mt < 4; ++mt) {
                bf16x8 af = *(const bf16x8*)(smem + AFR_B
                                + swzA(((mt * 8 + kt) << 10) + lane * 16));
                gacc[mt][0] = __builtin_amdgcn_mfma_f32_16x16x32_bf16(af, bw0, gacc[mt][0], 0, 0, 0);
                gacc[mt][1] = __builtin_amdgcn_mfma_f32_16x16x32_bf16(af, bw1, gacc[mt][1], 0, 0, 0);
            }
        }
        if (w == 7 && (fl == 10 || fl == 11)) {      // cols 250 / 251
            float* dst = (float*)(smem + (fl == 10 ? OFF_AS : OFF_AD));
#pragma unroll
            for (int mt = 0; mt < 4; ++mt) {
                f32x4 v = gacc[mt][1];
#pragma unroll
                for (int q = 0; q < 4; ++q) dst[mt * 16 + fh * 4 + q] = v[q];
            }
        }
        bar_lgkm();   // bar1: AFR reads + AS/AD writes done

        // ---- B: tl(i+1) load; DMA(i+1) -> slab; Hs write; softmax;
        //         tl write; bar2 ----
        float2 tl = {0.f, 0.f};
        if (pfen) {
            if (tid < 63) tl = *(const float2*)(xnext + tid * F_DIM + 248);
#pragma unroll
            for (int rr = 0; rr < 8; ++rr) {
                int r = w * 8 + rr;
                if (r < 63 && lane < 62)
                    dma16(xnext + r * F_DIM + lane * 4, smem + SLAB + r * ROWB);
            }
        }
        // Hs[f][s] bf16 (swz), f<250
#pragma unroll
        for (int mt = 0; mt < 4; ++mt) {
            int s0 = mt * 16 + fh * 4;
#pragma unroll
            for (int nti = 0; nti < 2; ++nti) {
                int f = w * 32 + nti * 16 + fl;
                if (f < F_DIM) {
                    f32x4 v = gacc[mt][nti];
                    bf16x4 hv = { (bf16)v.x, (bf16)v.y, (bf16)v.z, (bf16)v.w };
                    *(bf16x4*)(smem + swz(HSB + f * 128 + s0 * 2)) = hv;
                }
            }
        }
        // softmax (block-wide, once): thread=(d=tid>>3, c=tid&7)
        {
            const float* AS  = (const float*)(smem + OFF_AS);
            const float* ADp = (const float*)(smem + OFF_AD);
            int d = tid >> 3;
            int c = tid & 7;
            float ad_v = ADp[d];
            f32x4 a0 = *(const f32x4*)(AS + c * 8);
            f32x4 a1 = *(const f32x4*)(AS + c * 8 + 4);
            float p[8];
#pragma unroll
            for (int k = 0; k < 4; ++k) {
                float e;
                e = a0[k] + ad_v; p[k]     = (e > 0.f) ? e : NEG_SLOPE * e;
                e = a1[k] + ad_v; p[4 + k] = (e > 0.f) ? e : NEG_SLOPE * e;
            }
            if (c == 7) p[7] = -3.0e38f;   // s=63 excluded (63 sources)
            float md = p[0];
#pragma unroll
            for (int k = 1; k < 8; ++k) md = fmaxf(md, p[k]);
            md = fmaxf(md, __shfl_xor(md, 1));
            md = fmaxf(md, __shfl_xor(md, 2));
            md = fmaxf(md, __shfl_xor(md, 4));
            float sum = 0.f;
#pragma unroll
            for (int k = 0; k < 8; ++k) { p[k] = __expf(p[k] - md); sum += p[k]; }
            sum += __shfl_xor(sum, 1);
            sum += __shfl_xor(sum, 2);
            sum += __shfl_xor(sum, 4);
            float rz = 1.f / sum;
            bf16x8 pkv;
#pragma unroll
            for (int k = 0; k < 8; ++k) pkv[k] = (bf16)(p[k] * rz);
            *(bf16x8*)(smem + swz(ALPHA_B + d * 128 + c * 16)) = pkv;
        }
        if (pfen && tid < 63)
            *(float2*)(smem + SLAB + tid * ROWB + 992) = tl;
        bar_lgkm();   // bar2: Hs + alpha + slab-tail visible (DMA flying)

        // ---- D: GEMM2 (Hs + alpha); stores; vmcnt(32); conv(i+1); bar3 ----
#pragma unroll
        for (int mt = 0; mt < 4; ++mt) {
            gacc[mt][0] = (f32x4){0.f, 0.f, 0.f, 0.f};
            gacc[mt][1] = (f32x4){0.f, 0.f, 0.f, 0.f};
        }
#pragma unroll
        for (int ks = 0; ks < 2; ++ks) {
            int kk = ks * 32 + fh * 8;
            bf16x8 hbf0 = *(const bf16x8*)(smem + swz(HSB + (w * 32 + fl)      * 128 + kk * 2));
            bf16x8 hbf1 = *(const bf16x8*)(smem + swz(HSB + (w * 32 + fl + 16) * 128 + kk * 2));
#pragma unroll
            for (int mt = 0; mt < 4; ++mt) {
                bf16x8 aal = *(const bf16x8*)(smem + swz(ALPHA_B + (mt * 16 + fl) * 128 + kk * 2));
                gacc[mt][0] = __builtin_amdgcn_mfma_f32_16x16x32_bf16(aal, hbf0, gacc[mt][0], 0, 0, 0);
                gacc[mt][1] = __builtin_amdgcn_mfma_f32_16x16x32_bf16(aal, hbf1, gacc[mt][1], 0, 0, 0);
            }
        }
        float* ob = out + (size_t)b * (C_NODES * F_DIM);
#pragma unroll
        for (int mt = 0; mt < 4; ++mt) {
#pragma unroll
            for (int q = 0; q < 4; ++q) {
                int r = mt * 16 + fh * 4 + q;
                if (r < C_NODES) {
                    int f = w * 32 + fl;
                    ob[r * F_DIM + f] = gacc[mt][0][q] + bv0;
                    f += 16;
                    if (f < F_DIM) ob[r * F_DIM + f] = gacc[mt][1][q] + bv1;
                }
            }
        }
        if (pfen) {
            // 8 DMA ops are OLDER than the 32 stores just issued: vmcnt(32)
            // == "all DMA landed, stores may keep flying".
            asm volatile("s_waitcnt vmcnt(32)" ::: "memory");
            conv_rows(smem, w, lane);   // wave-local: own DMA rows + wave-0
                                        // tail crossed bar2
        }
        bar_lgkm();   // bar3: AFR(i+1) visible; alpha/Hs reads drained
    }
}

extern "C" void kernel_launch(void* const* d_in, const int* in_sizes, int n_in,
                              void* d_out, int out_size, void* d_ws, size_t ws_size,
                              hipStream_t stream) {
    const float* x       = (const float*)d_in[0];
    const float* W       = (const float*)d_in[1];
    const float* att_src = (const float*)d_in[2];
    const float* att_dst = (const float*)d_in[3];
    const float* bias    = (const float*)d_in[4];
    float* out = (float*)d_out;
    bf16* Wp = (bf16*)d_ws;   // 65536 bf16 = 128 KB packed W (+score cols)

    gat_prep<<<256, 256, 0, stream>>>(W, att_src, att_dst, Wp);
    gat_main<<<256, 512, 0, stream>>>(x, Wp, bias, out);
}